// Round 3
// baseline (170.077 us; speedup 1.0000x reference)
//
#include <hip/hip_runtime.h>

// (B,P,C,H,W)=(256,10,32,8,8); Tm=19, Ta=10, hw=64. All I/O fp32.
// Horner: A_0=[F_0;1]; A_{p+1}=A_p*M_p+[F_{p+1};1] (p=0..8) -> A_9=[G;W]
// out[b,t,c,j] = (G[c,:].M_t[:,j]) / (W.M_t[:,j] + eps)
//
// v13 (from v12): compiler kept VGPR=44 and sank every source-level phase-2
// prefetch -> phase-2 L2 latency (~200-500cy x 128 loads/wave) was never
// pipelined. Changes:
//  1. Phase 2a/2b: explicit 2-ring register pipeline (8 x float4 batches,
//     rA/rB alternation, all indices static), each load batch pinned with
//     sched_barrier(0) so it cannot be sunk. Batch kb+1 in flight across
//     batch kb's ~370cy of FMAs. 2a batch 0 issued before the handoff
//     barrier. VGPR target ~100 (launch_bounds(512,2) caps at 128).
//  2. Phase 1: 2-step-ahead global prefetch (nh/nf) -> ~1400cy in flight,
//     covers HBM-miss latency (FETCH says ~2/3 of sim comes from HBM).
//  3. p=8 peel + dead pf[8] removed.

#define EPSV 1e-6f

__device__ __forceinline__ float rdlane(float v, int k) {
    return __int_as_float(__builtin_amdgcn_readlane(__float_as_int(v), k));
}

#define P2_LOAD(DST, MT, KB1, JJ)                                             \
    {                                                                         \
        _Pragma("unroll")                                                     \
        for (int q = 0; q < 8; ++q)                                           \
            DST[q] = *(const float4*)&MT[((KB1) * 8 + q) * 64 + (JJ)];        \
        __builtin_amdgcn_sched_barrier(0);                                    \
    }

#define P2A_COMP(SRC, KB)                                                     \
    {                                                                         \
        _Pragma("unroll")                                                     \
        for (int q = 0; q < 8; ++q) {                                         \
            const int k   = (KB) * 8 + q;                                     \
            const float4 g  = *(const float4*)&Gt[k * 20 + rr];               \
            const float  wk = Gt[k * 20 + 16];                                \
            const float4 m  = SRC[q];                                         \
            wv0 += wk * m.x; wv1 += wk * m.y; wv2 += wk * m.z; wv3 += wk * m.w; \
            acc[0]  += g.x*m.x; acc[1]  += g.x*m.y; acc[2]  += g.x*m.z; acc[3]  += g.x*m.w; \
            acc[4]  += g.y*m.x; acc[5]  += g.y*m.y; acc[6]  += g.y*m.z; acc[7]  += g.y*m.w; \
            acc[8]  += g.z*m.x; acc[9]  += g.z*m.y; acc[10] += g.z*m.z; acc[11] += g.z*m.w; \
            acc[12] += g.w*m.x; acc[13] += g.w*m.y; acc[14] += g.w*m.z; acc[15] += g.w*m.w; \
        }                                                                     \
    }

#define P2B_COMP(SRC, KB)                                                     \
    {                                                                         \
        _Pragma("unroll")                                                     \
        for (int q = 0; q < 8; ++q) {                                         \
            const int k   = (KB) * 8 + q;                                     \
            const float  g  = Gt[k * 20 + row];                               \
            const float  wk = Gt[k * 20 + 16];                                \
            const float4 m  = SRC[q];                                         \
            ac0 += g * m.x;  ac1 += g * m.y;  ac2 += g * m.z;  ac3 += g * m.w; \
            wv0 += wk * m.x; wv1 += wk * m.y; wv2 += wk * m.z; wv3 += wk * m.w; \
        }                                                                     \
    }

__global__ __launch_bounds__(512, 2) void k_fused(
    const float* __restrict__ feats,   // (256,10,32,64)
    const float* __restrict__ sim,     // (256,19,64,64)
    float* __restrict__ out)           // (2560,32,64)
{
    __shared__ __attribute__((aligned(16))) float Mb[2][4096];  // 32KB dbuf
    __shared__ __attribute__((aligned(16))) float Gt[1280];     // 5KB handoff

    const int tid  = threadIdx.x;
    const int lane = tid & 63;
    const int wave = tid >> 6;          // 0..7
    const int b    = blockIdx.x & 255;  // pair (b, b+256) -> same XCD
    const int h    = blockIdx.x >> 8;   // row-half of the batch

    const float* fb = feats + (size_t)b * 20480;   // 10*32*64
    const float* sb = sim   + (size_t)b * 77824;   // 19*64*64

    // ---- stage M_0 into Mb[0]; prefetch M_1 into registers (2-ahead) ----
    {
        const float4 s0 = *(const float4*)&sb[tid * 4];
        const float4 s1 = *(const float4*)&sb[2048 + tid * 4];
        *(float4*)&Mb[0][tid * 4]        = s0;
        *(float4*)&Mb[0][2048 + tid * 4] = s1;
    }
    float4 nh0 = *(const float4*)&sb[4096 + tid * 4];
    float4 nh1 = *(const float4*)&sb[4096 + 2048 + tid * 4];

    // ---- phase 1: wave owns rows r0,r0+1 (wave 7 also W). ----
    const int r0 = 16 * h + 2 * wave;
    float a0 = fb[(r0 + 0) * 64 + lane];
    float a1 = fb[(r0 + 1) * 64 + lane];
    float aw = 1.0f;

    __syncthreads();                    // M_0 visible

    for (int p = 0; p < 9; ++p) {
        // 2-ahead: issue M_{p+2} now, it lands while M_{p+1} (in nh) is
        // written and consumed. ~1400cy in flight.
        float4 nf0, nf1;
        if (p < 7) {
            const float* __restrict__ Mn = sb + (p + 2) * 4096;
            nf0 = *(const float4*)&Mn[tid * 4];
            nf1 = *(const float4*)&Mn[2048 + tid * 4];
        }
        const float* __restrict__ F = fb + (p + 1) * 2048;
        const float f0 = F[(r0 + 0) * 64 + lane];
        const float f1 = F[(r0 + 1) * 64 + lane];
        __builtin_amdgcn_sched_barrier(0);   // pin all loads before compute
        const float* __restrict__ Mc = Mb[p & 1];

        float c0 = 0.f, c1 = 0.f, cw = 0.f;
        if (wave == 7) {                // wave-uniform branch
            #pragma unroll
            for (int k = 0; k < 64; ++k) {
                const float m = Mc[k * 64 + lane];   // ds_read_b32, imm offset
                c0 += rdlane(a0, k) * m;
                c1 += rdlane(a1, k) * m;
                cw += rdlane(aw, k) * m;
            }
        } else {
            #pragma unroll
            for (int k = 0; k < 64; ++k) {
                const float m = Mc[k * 64 + lane];
                c0 += rdlane(a0, k) * m;
                c1 += rdlane(a1, k) * m;
            }
        }
        a0 = c0 + f0; a1 = c1 + f1; aw = cw + 1.0f;

        if (p < 8) {
            float* Mw = Mb[(p + 1) & 1];       // other buffer: no reader-wait
            *(float4*)&Mw[tid * 4]        = nh0;
            *(float4*)&Mw[2048 + tid * 4] = nh1;
            __syncthreads();
            nh0 = nf0; nh1 = nf1;              // p=7: dead copy, unused at p=8
        }
    }

    // ---- phase 2a setup: issue first Mt batch BEFORE the handoff barrier ----
    const int rr = (lane >> 4) * 4;     // 0,4,8,12 (within the half)
    const int jj = (lane & 15) * 4;
    const float* __restrict__ Mt_a = sb + (9 + wave) * 4096;

    float4 rA[8], rB[8];
    #pragma unroll
    for (int q = 0; q < 8; ++q) rA[q] = *(const float4*)&Mt_a[q * 64 + jj];
    __builtin_amdgcn_sched_barrier(0);

    // ---- handoff: half G + W -> LDS (k = lane, transposed writes) ----
    Gt[lane * 20 + 2 * wave + 0] = a0;
    Gt[lane * 20 + 2 * wave + 1] = a1;
    if (wave == 7) Gt[lane * 20 + 16] = aw;
    __syncthreads();

    // ---- phase 2a: job t=wave, 16 rows x 64 cols, ring-pipelined loads ----
    {
        float acc[16];
        #pragma unroll
        for (int i = 0; i < 16; ++i) acc[i] = 0.f;
        float wv0 = 0.f, wv1 = 0.f, wv2 = 0.f, wv3 = 0.f;

        P2_LOAD(rB, Mt_a, 1, jj)  P2A_COMP(rA, 0)
        P2_LOAD(rA, Mt_a, 2, jj)  P2A_COMP(rB, 1)
        P2_LOAD(rB, Mt_a, 3, jj)  P2A_COMP(rA, 2)
        P2_LOAD(rA, Mt_a, 4, jj)  P2A_COMP(rB, 3)
        P2_LOAD(rB, Mt_a, 5, jj)  P2A_COMP(rA, 4)
        P2_LOAD(rA, Mt_a, 6, jj)  P2A_COMP(rB, 5)
        P2_LOAD(rB, Mt_a, 7, jj)  P2A_COMP(rA, 6)
                                  P2A_COMP(rB, 7)

        float4 rw;
        rw.x = 1.f / (wv0 + EPSV); rw.y = 1.f / (wv1 + EPSV);
        rw.z = 1.f / (wv2 + EPSV); rw.w = 1.f / (wv3 + EPSV);

        float* ob = out + ((size_t)b * 10 + wave) * 2048;
        #pragma unroll
        for (int i = 0; i < 4; ++i) {
            float4 o;
            o.x = acc[i * 4 + 0] * rw.x;
            o.y = acc[i * 4 + 1] * rw.y;
            o.z = acc[i * 4 + 2] * rw.z;
            o.w = acc[i * 4 + 3] * rw.w;
            *(float4*)&ob[(16 * h + rr + i) * 64 + jj] = o;
        }
    }

    // ---- phase 2b: t=8,9 as 8 quarter-jobs (4 rows x 64 cols), same ring ----
    {
        const int t   = 8 + (wave >> 2);               // waves 0-3 -> 8, 4-7 -> 9
        const int row = (wave & 3) * 4 + (lane >> 4);  // 0..15 within the half
        const float* __restrict__ Mt_b = sb + (9 + t) * 4096;

        float ac0 = 0.f, ac1 = 0.f, ac2 = 0.f, ac3 = 0.f;
        float wv0 = 0.f, wv1 = 0.f, wv2 = 0.f, wv3 = 0.f;

        P2_LOAD(rA, Mt_b, 0, jj)
        P2_LOAD(rB, Mt_b, 1, jj)  P2B_COMP(rA, 0)
        P2_LOAD(rA, Mt_b, 2, jj)  P2B_COMP(rB, 1)
        P2_LOAD(rB, Mt_b, 3, jj)  P2B_COMP(rA, 2)
        P2_LOAD(rA, Mt_b, 4, jj)  P2B_COMP(rB, 3)
        P2_LOAD(rB, Mt_b, 5, jj)  P2B_COMP(rA, 4)
        P2_LOAD(rA, Mt_b, 6, jj)  P2B_COMP(rB, 5)
        P2_LOAD(rB, Mt_b, 7, jj)  P2B_COMP(rA, 6)
                                  P2B_COMP(rB, 7)

        float4 o;
        o.x = ac0 * (1.f / (wv0 + EPSV));
        o.y = ac1 * (1.f / (wv1 + EPSV));
        o.z = ac2 * (1.f / (wv2 + EPSV));
        o.w = ac3 * (1.f / (wv3 + EPSV));

        float* ob = out + ((size_t)b * 10 + t) * 2048;
        *(float4*)&ob[(16 * h + row) * 64 + jj] = o;
    }
}

extern "C" void kernel_launch(void* const* d_in, const int* in_sizes, int n_in,
                              void* d_out, int out_size, void* d_ws, size_t ws_size,
                              hipStream_t stream) {
    const float* feats = (const float*)d_in[0];
    const float* sim   = (const float*)d_in[1];
    k_fused<<<512, 512, 0, stream>>>(feats, sim, (float*)d_out);
}

// Round 4
// 169.282 us; speedup vs baseline: 1.0047x; 1.0047x over previous
//
#include <hip/hip_runtime.h>

// (B,P,C,H,W)=(256,10,32,8,8); Tm=19, Ta=10, hw=64. All I/O fp32.
// Horner: A_0=[F_0;1]; A_{p+1}=A_p*M_p+[F_{p+1};1] (p=0..8) -> A_9=[G;W]
// out[b,t,c,j] = (G[c,:].M_t[:,j]) / (W.M_t[:,j] + eps)
//
// v14 (from v12; v13's register rings spilled and regressed): attack the
// same latency holes with global_load_lds DMA (zero VGPR cost) + counted
// vmcnt waits (T4):
//  1. Phase 1 staging via 2x global_load_lds/thread into the other dbuf
//     half, issued at step top. No VGPR round-trip, nothing to sink.
//  2. Phase 2a/2b: per-wave private 2x2KB LDS ring (P2[8][1024], +32KB);
//     Mt consumed in 8-row batches, batch kb+2 in flight while computing
//     kb; uniform s_waitcnt vmcnt(2) (inline asm, memory clobber) before
//     each consume; lgkmcnt(0) before each DMA guards buffer reuse.
//  LDS 69KB -> still 2 blocks/CU. Accumulation order identical to v12.

#define EPSV 1e-6f

#define GLOAD_LDS(G, L)                                                       \
    __builtin_amdgcn_global_load_lds(                                         \
        (const __attribute__((address_space(1))) void*)(G),                   \
        (__attribute__((address_space(3))) void*)(L), 16, 0, 0)

#define WAITV2() asm volatile("s_waitcnt vmcnt(2)" ::: "memory")
#define WAITV0() asm volatile("s_waitcnt vmcnt(0)" ::: "memory")
#define WAITL0() asm volatile("s_waitcnt lgkmcnt(0)" ::: "memory")

__device__ __forceinline__ float rdlane(float v, int k) {
    return __int_as_float(__builtin_amdgcn_readlane(__float_as_int(v), k));
}

// stage one 16KB matrix SRC into Mb[BUF]: 512 thr x 2 x 16B DMA.
// wave w's 64 lanes cover floats [256w,256w+256) then [2048+256w, ...).
#define STAGE_DMA(SRC, BUF)                                                   \
    {                                                                         \
        GLOAD_LDS((SRC) + tid * 4,        &Mb[BUF][wave * 256]);              \
        GLOAD_LDS((SRC) + 2048 + tid * 4, &Mb[BUF][2048 + wave * 256]);       \
    }

// DMA 8 rows (2KB) of MT, batch KB, into P2[wave] half (KB&1).
// lane l covers row KB*8 + 4i + (l>>4), cols (l&15)*4..+4.
#define P2_DMA(MT, KB)                                                        \
    {                                                                         \
        WAITL0();                                                             \
        const float* _s = (MT) + ((KB) * 8 + (lane >> 4)) * 64 + (lane & 15) * 4; \
        GLOAD_LDS(_s,       &P2[wave][((KB) & 1) * 512]);                     \
        GLOAD_LDS(_s + 256, &P2[wave][((KB) & 1) * 512 + 256]);               \
    }

#define P2A_COMP8(KB)                                                         \
    {                                                                         \
        _Pragma("unroll")                                                     \
        for (int q = 0; q < 8; ++q) {                                         \
            const int k = (KB) * 8 + q;                                       \
            const float4 g  = *(const float4*)&Gt[k * 20 + rr];               \
            const float  wk = Gt[k * 20 + 16];                                \
            const float4 m  = *(const float4*)&P2[wave][((KB) & 1) * 512 + q * 64 + jj]; \
            wv0 += wk * m.x; wv1 += wk * m.y; wv2 += wk * m.z; wv3 += wk * m.w; \
            acc[0]  += g.x*m.x; acc[1]  += g.x*m.y; acc[2]  += g.x*m.z; acc[3]  += g.x*m.w; \
            acc[4]  += g.y*m.x; acc[5]  += g.y*m.y; acc[6]  += g.y*m.z; acc[7]  += g.y*m.w; \
            acc[8]  += g.z*m.x; acc[9]  += g.z*m.y; acc[10] += g.z*m.z; acc[11] += g.z*m.w; \
            acc[12] += g.w*m.x; acc[13] += g.w*m.y; acc[14] += g.w*m.z; acc[15] += g.w*m.w; \
        }                                                                     \
    }

#define P2B_COMP8(KB)                                                         \
    {                                                                         \
        _Pragma("unroll")                                                     \
        for (int q = 0; q < 8; ++q) {                                         \
            const int k = (KB) * 8 + q;                                       \
            const float  g  = Gt[k * 20 + row];                               \
            const float  wk = Gt[k * 20 + 16];                                \
            const float4 m  = *(const float4*)&P2[wave][((KB) & 1) * 512 + q * 64 + jj]; \
            ac0 += g * m.x;  ac1 += g * m.y;  ac2 += g * m.z;  ac3 += g * m.w; \
            wv0 += wk * m.x; wv1 += wk * m.y; wv2 += wk * m.z; wv3 += wk * m.w; \
        }                                                                     \
    }

__global__ __launch_bounds__(512, 2) void k_fused(
    const float* __restrict__ feats,   // (256,10,32,64)
    const float* __restrict__ sim,     // (256,19,64,64)
    float* __restrict__ out)           // (2560,32,64)
{
    __shared__ __attribute__((aligned(16))) float Mb[2][4096];  // 32KB dbuf
    __shared__ __attribute__((aligned(16))) float Gt[1280];     // 5KB handoff
    __shared__ __attribute__((aligned(16))) float P2[8][1024];  // 32KB p2 rings

    const int tid  = threadIdx.x;
    const int lane = tid & 63;
    const int wave = tid >> 6;          // 0..7
    const int b    = blockIdx.x & 255;  // pair (b, b+256) -> same XCD
    const int h    = blockIdx.x >> 8;   // row-half of the batch

    const float* fb = feats + (size_t)b * 20480;   // 10*32*64
    const float* sb = sim   + (size_t)b * 77824;   // 19*64*64

    // phase-2a geometry (needed early for the p=8 DMA prologue)
    const int rr = (lane >> 4) * 4;     // 0,4,8,12 (within the half)
    const int jj = (lane & 15) * 4;
    const float* __restrict__ Mt_a = sb + (9 + wave) * 4096;

    // ---- stage M_0 into Mb[0] via DMA ----
    STAGE_DMA(sb, 0);

    // ---- phase 1: wave owns rows r0,r0+1 (wave 7 also W). ----
    const int r0 = 16 * h + 2 * wave;
    float a0 = fb[(r0 + 0) * 64 + lane];
    float a1 = fb[(r0 + 1) * 64 + lane];
    float aw = 1.0f;

    __syncthreads();                    // vmcnt drained: M_0 visible

    for (int p = 0; p < 9; ++p) {
        if (p < 8) {
            // DMA M_{p+1} straight into the other buffer; lands during the
            // ~700cy of compute below; barrier drains it.
            STAGE_DMA(sb + (p + 1) * 4096, (p + 1) & 1);
        } else {
            // p=8: warm up phase 2a's first two ring batches instead.
            P2_DMA(Mt_a, 0);
            P2_DMA(Mt_a, 1);
        }
        const float* __restrict__ F = fb + (p + 1) * 2048;
        const float f0 = F[(r0 + 0) * 64 + lane];
        const float f1 = F[(r0 + 1) * 64 + lane];
        const float* __restrict__ Mc = &Mb[p & 1][0];

        float c0 = 0.f, c1 = 0.f, cw = 0.f;
        if (wave == 7) {                // wave-uniform branch
            #pragma unroll
            for (int k = 0; k < 64; ++k) {
                const float m = Mc[k * 64 + lane];   // ds_read_b32, imm offset
                c0 += rdlane(a0, k) * m;
                c1 += rdlane(a1, k) * m;
                cw += rdlane(aw, k) * m;
            }
        } else {
            #pragma unroll
            for (int k = 0; k < 64; ++k) {
                const float m = Mc[k * 64 + lane];
                c0 += rdlane(a0, k) * m;
                c1 += rdlane(a1, k) * m;
            }
        }
        a0 = c0 + f0; a1 = c1 + f1; aw = cw + 1.0f;

        if (p < 8) __syncthreads();
    }

    // ---- handoff: half G + W -> LDS (k = lane, transposed writes) ----
    Gt[lane * 20 + 2 * wave + 0] = a0;
    Gt[lane * 20 + 2 * wave + 1] = a1;
    if (wave == 7) Gt[lane * 20 + 16] = aw;
    __syncthreads();                    // also drains P2 batches 0,1

    // ---- phase 2a: job t=wave, 16x64, LDS ring + counted vmcnt ----
    {
        float acc[16];
        #pragma unroll
        for (int i = 0; i < 16; ++i) acc[i] = 0.f;
        float wv0 = 0.f, wv1 = 0.f, wv2 = 0.f, wv3 = 0.f;

        P2A_COMP8(0)  P2_DMA(Mt_a, 2)            // outst: {2}
        P2A_COMP8(1)  P2_DMA(Mt_a, 3)            // outst: {2,3}
        WAITV2(); P2A_COMP8(2)  P2_DMA(Mt_a, 4)
        WAITV2(); P2A_COMP8(3)  P2_DMA(Mt_a, 5)
        WAITV2(); P2A_COMP8(4)  P2_DMA(Mt_a, 6)
        WAITV2(); P2A_COMP8(5)  P2_DMA(Mt_a, 7)
        WAITV2(); P2A_COMP8(6)
        WAITV0(); P2A_COMP8(7)

        float4 rw;
        rw.x = 1.f / (wv0 + EPSV); rw.y = 1.f / (wv1 + EPSV);
        rw.z = 1.f / (wv2 + EPSV); rw.w = 1.f / (wv3 + EPSV);

        float* ob = out + ((size_t)b * 10 + wave) * 2048;
        #pragma unroll
        for (int i = 0; i < 4; ++i) {
            float4 o;
            o.x = acc[i * 4 + 0] * rw.x;
            o.y = acc[i * 4 + 1] * rw.y;
            o.z = acc[i * 4 + 2] * rw.z;
            o.w = acc[i * 4 + 3] * rw.w;
            *(float4*)&ob[(16 * h + rr + i) * 64 + jj] = o;
        }
    }

    // ---- phase 2b: t=8,9 as 8 quarter-jobs (4 rows x 64 cols), same ring ----
    {
        const int t   = 8 + (wave >> 2);               // waves 0-3 -> 8, 4-7 -> 9
        const int row = (wave & 3) * 4 + (lane >> 4);  // 0..15 within the half
        const float* __restrict__ Mt_b = sb + (9 + t) * 4096;

        float ac0 = 0.f, ac1 = 0.f, ac2 = 0.f, ac3 = 0.f;
        float wv0 = 0.f, wv1 = 0.f, wv2 = 0.f, wv3 = 0.f;

        P2_DMA(Mt_b, 0)                          // FIFO: stores(4), b0, b1
        P2_DMA(Mt_b, 1)
        WAITV2(); P2B_COMP8(0)  P2_DMA(Mt_b, 2)  // waits stores+b0 (older)
        WAITV2(); P2B_COMP8(1)  P2_DMA(Mt_b, 3)
        WAITV2(); P2B_COMP8(2)  P2_DMA(Mt_b, 4)
        WAITV2(); P2B_COMP8(3)  P2_DMA(Mt_b, 5)
        WAITV2(); P2B_COMP8(4)  P2_DMA(Mt_b, 6)
        WAITV2(); P2B_COMP8(5)  P2_DMA(Mt_b, 7)
        WAITV2(); P2B_COMP8(6)
        WAITV0(); P2B_COMP8(7)

        float4 o;
        o.x = ac0 * (1.f / (wv0 + EPSV));
        o.y = ac1 * (1.f / (wv1 + EPSV));
        o.z = ac2 * (1.f / (wv2 + EPSV));
        o.w = ac3 * (1.f / (wv3 + EPSV));

        float* ob = out + ((size_t)b * 10 + t) * 2048;
        *(float4*)&ob[(16 * h + row) * 64 + jj] = o;
    }
}

extern "C" void kernel_launch(void* const* d_in, const int* in_sizes, int n_in,
                              void* d_out, int out_size, void* d_ws, size_t ws_size,
                              hipStream_t stream) {
    const float* feats = (const float*)d_in[0];
    const float* sim   = (const float*)d_in[1];
    k_fused<<<512, 512, 0, stream>>>(feats, sim, (float*)d_out);
}